// Round 9
// baseline (1122.920 us; speedup 1.0000x reference)
//
#include <hip/hip_runtime.h>

// Problem constants
#define HH 2048
#define WW 2048
#define WSK 4095            // real skewed columns
#define WSKP 4096           // padded (col 4095 = dump column; never consumed)
#define BLKS 8              // pipelined blocks (CUs)
#define NW  4               // waves per block
#define NT  (NW * 64)       // 256 threads, 1 row/thread
#define KCH 32              // columns per chunk
#define NCH (WSKP / KCH)    // 128 chunks
#define FC_IN 1024
#define FC_OUT 10

typedef float f32x4 __attribute__((ext_vector_type(4)));

// R13: FUSE FC INTO THE SCAN (R12 post-mortem: 6 rounds of scan surgery all
// lost to R6's 438us -- the ~150cyc/col stall is robust; use it as free
// bandwidth instead). Each lane holds h[r][c] = unskewed(r, c-r) in a
// register every column -> accumulate acc[j] += h * fcw[j][(c-r)&1023]
// (10 LDS reads + 10 FMAs, independent of the tanh chain = stall filler);
// flush 10 outputs when c-r hits 1023 / 2047 (wave branch, ~3% of columns).
// Deleted: fc kernel, the 32MB acts write, the 32MB fc read, one launch.
// Boundary handoff: R6's PROVEN flag+acquire/release protocol; publisher
// (wave3 lane63) stores h in-place into its own consumed inp cell (R6's
// in-place trick, one row only). Flags: 4KB carved from inp column 4095
// (skew skips it, publisher skips it, its loads feed only the never-
// consumed dump column; memsetAsync resets it each launch).

// tanh(x) = 1 - 2/(exp2(x*2/ln2)+1); caller passes pre-scaled xs = x*2/ln2.
__device__ __forceinline__ float tanh_pre(float xs) {
  float e = __builtin_amdgcn_exp2f(xs);
  float r = __builtin_amdgcn_rcpf(e + 1.0f);
  return __builtin_fmaf(-2.0f, r, 1.0f);
}

// Full-wave shift-up-by-1 via DPP wave_shr:1 (verified R5: exact absmax).
__device__ __forceinline__ float wave_shr1(float src, float old) {
  int r = __builtin_amdgcn_update_dpp(
      __builtin_bit_cast(int, old), __builtin_bit_cast(int, src),
      0x138 /*wave_shr:1*/, 0xF, 0xF, false);
  return __builtin_bit_cast(float, r);
}

__device__ __forceinline__ float rlane(float v, int l) {
  return __builtin_bit_cast(float,
      __builtin_amdgcn_readlane(__builtin_bit_cast(int, v), l));
}

// inp[c*HH+r] = S*(w*img[r][c-r] + b_in + b_state), bias-only off-image.
// Column-major (R6's fast layout: per-column loads are 256B coalesced).
// Col 4095 SKIPPED: its cells host the flags (scan never consumes col 4095).
__global__ __launch_bounds__(256) void skew_kernel(
    const float* __restrict__ img, const float* __restrict__ w_in,
    const float* __restrict__ b_in, const float* __restrict__ b_state,
    float* __restrict__ inp) {
  const float S = 2.88539008177792681472f;   // 2/ln(2)
  const float ws = w_in[0] * S;
  const float Cs = (b_in[0] + b_state[0]) * S;
  int gid = blockIdx.x * 256 + threadIdx.x;  // gid = c*HH + r
  int r = gid & (HH - 1);
  int c = gid >> 11;
  int idx = c - r;
  float v = Cs;
  if ((unsigned)idx < (unsigned)WW) v = fmaf(ws, img[(size_t)r * WW + idx], Cs);
  if (c != WSKP - 1) inp[gid] = v;
}

// 8-block x 4-wave wavefront-pipelined scan + fused FC, 1 row/thread.
// Ring semantics (verified R2-R5): ring[e&1][w][i] = wave w's h AFTER column
// c0+i-1; slot 0 at chunk start, slot i+1 after column i.
// inp/acts same buffer: loads touch chunk ch+1 (own rows), publisher stores
// chunk ch (own row, already consumed) -> disjoint; consumer gathers the
// producer's row under acquire (fresh). Clamped final-chunk reload may read
// flag bytes as floats -- feeds only the never-consumed dump column.
__global__ __launch_bounds__(NT) void scan_kernel(
    const float* __restrict__ w_state, const float* __restrict__ inp,
    float* __restrict__ acts, const float* __restrict__ fc_w,
    const float* __restrict__ fc_b, float* __restrict__ out,
    unsigned* __restrict__ flags) {
  const int t = threadIdx.x;
  const int wv = t >> 6;
  const int lane = t & 63;
  const int blk = blockIdx.x;
  const int r = blk * NT + t;                // global row (1 per thread)
  const int w0 = blk * NT + wv * 64;         // wave's first row

  const float S = 2.88539008177792681472f;
  const float k0s = w_state[0] * S;
  const float k1s = w_state[1] * S;

  __shared__ float ring[2][NW][KCH];         // 1 KB
  __shared__ float fcw[FC_OUT * FC_IN];      // 40 KB

  // Stage fc_w into LDS (coalesced float4), fc_b into registers (uniform
  // address -> scalar loads).
  for (int i = t; i < (FC_OUT * FC_IN) / 4; i += NT)
    ((f32x4*)fcw)[i] = ((const f32x4*)fc_w)[i];
  float fcb[FC_OUT];
  #pragma unroll
  for (int j = 0; j < FC_OUT; ++j) fcb[j] = fc_b[j];

  float acc[FC_OUT];
  #pragma unroll
  for (int j = 0; j < FC_OUT; ++j) acc[j] = 0.0f;

  float h = 0.0f;
  const float* colp_in = inp + r;
  float* colp_out = acts + r;                // publisher (wave3 lane63) only

  // Prime prefetch registers with chunk 0 (R6's exact pattern).
  float pf[KCH];
  #pragma unroll
  for (int d = 0; d < KCH; ++d) pf[d] = colp_in[(size_t)d * HH];

  const unsigned* upflag = flags + (blk - 1) * NCH;
  unsigned* myflag = flags + blk * NCH;
  const float* uprow = blk > 0 ? acts + (blk * NT - 1) : acts;

  __syncthreads();                           // fcw staged

  // Startup slack + chunk-0 boundary gather (wave 0, blk>0 only).
  // bvec lane i (i<32) = neighbor-row h AFTER column c0+i-1.
  float bvec = 0.0f;
  if (wv == 0 && blk > 0) {
    while (__hip_atomic_load(upflag + 1, __ATOMIC_ACQUIRE,
                             __HIP_MEMORY_SCOPE_AGENT) != 2u)
      __builtin_amdgcn_s_sleep(2);
    if (lane >= 1 && lane < KCH) bvec = uprow[(size_t)(lane - 1) * HH];
  }

  const bool pub = (wv == NW - 1) && (lane == 63);
  const bool rw = (lane == 63) && (wv != NW - 1);

  for (int e = 0; e < NCH + NW - 1; ++e) {
    // Deferred release (wave3 lane63): flag for the chunk finished LAST
    // epoch; stores aged through a barrier -> drain off the critical path.
    if (wv == NW - 1 && blk + 1 < BLKS && lane == 63) {
      int chp = e - NW;
      if (chp >= 0)
        __hip_atomic_store(myflag + chp, (unsigned)(chp + 1),
                           __ATOMIC_RELEASE, __HIP_MEMORY_SCOPE_AGENT);
    }

    const int ch = e - wv;
    if (0 <= ch && ch < NCH) {
      const int c0 = ch * KCH;
      float bv = (wv == 0) ? bvec
                           : ring[(e & 1) ^ 1][wv - 1][lane & (KCH - 1)];
      if (rw) ring[e & 1][wv][0] = h;

      // Next-chunk prefetch base (clamped reload at final chunk, unused).
      const int cb = (ch + 1 < NCH ? ch + 1 : ch) * KCH;

      // FC relevance: any lane of this wave in-range for this chunk?
      // Lane r is in-range at col c iff 0 <= c-r < 2048.
      const bool rel = (c0 + KCH - 1 >= w0) && (c0 <= w0 + 63 + 2047);

      #pragma unroll
      for (int cc = 0; cc < KCH; ++cc) {
        float cur = pf[cc];
        pf[cc] = colp_in[(size_t)(cb + cc) * HH];

        float pv = rlane(bv, cc);
        float prev = wave_shr1(h, pv);       // prev[l]=h[l-1], prev[0]=pv
        h = tanh_pre(fmaf(k0s, prev, fmaf(k1s, h, cur)));

        if (rw && cc + 1 < KCH) ring[e & 1][wv][cc + 1] = h;
        // Boundary publish: one 4B store/col into own consumed inp cell.
        // Skip col 4095 (flag bytes live in that column's cells).
        if (pub && c0 + cc < WSK) colp_out[(size_t)(c0 + cc) * HH] = h;

        if (rel) {
          // Fused FC: h = unskewed(r, k01), k01 = c - r.
          int k01 = (c0 + cc) - r;
          bool inr = (unsigned)k01 < 2048u;
          float hv = inr ? h : 0.0f;
          int kk = k01 & 1023;
          #pragma unroll
          for (int j = 0; j < FC_OUT; ++j)
            acc[j] = fmaf(hv, fcw[j * FC_IN + kk], acc[j]);
          // Flush when a half completes (kk==1023): flat row 2r+(k01>>10).
          bool crossed = inr && (kk == 1023);
          if (__any(crossed ? 1 : 0)) {
            if (crossed) {
              int i2 = 2 * r + (k01 >> 10);
              #pragma unroll
              for (int j = 0; j < FC_OUT; ++j) {
                out[i2 * FC_OUT + j] = acc[j] + fcb[j];
                acc[j] = 0.0f;
              }
            }
          }
        }
      }

      // Wave 0: acquire-poll next chunk's flag, then gather its boundary
      // (plain strided loads; acquire invalidates, release wrote back).
      if (wv == 0 && blk > 0 && ch + 1 < NCH) {
        const unsigned want = (unsigned)(ch + 2);
        while (__hip_atomic_load(upflag + ch + 1, __ATOMIC_ACQUIRE,
                                 __HIP_MEMORY_SCOPE_AGENT) != want)
          __builtin_amdgcn_s_sleep(1);
        bvec = 0.0f;
        if (lane < KCH)
          bvec = uprow[(size_t)((ch + 1) * KCH + lane - 1) * HH];
      }
    }
    // LDS-only barrier: rotates the ring double-buffer WITHOUT draining
    // vmcnt, so pf reloads + boundary gather survive the epoch boundary.
    asm volatile("s_waitcnt lgkmcnt(0)\n\ts_barrier" ::: "memory");
  }

  // Final chunk's flag (in-loop publisher covers chp <= NCH-2).
  if (wv == NW - 1 && blk + 1 < BLKS && lane == 63)
    __hip_atomic_store(myflag + (NCH - 1), (unsigned)NCH,
                       __ATOMIC_RELEASE, __HIP_MEMORY_SCOPE_AGENT);
}

extern "C" void kernel_launch(void* const* d_in, const int* in_sizes, int n_in,
                              void* d_out, int out_size, void* d_ws, size_t ws_size,
                              hipStream_t stream) {
  const float* x       = (const float*)d_in[0];
  const float* w_in    = (const float*)d_in[1];
  const float* b_in    = (const float*)d_in[2];
  const float* w_state = (const float*)d_in[3];
  const float* b_state = (const float*)d_in[4];
  const float* fc_w    = (const float*)d_in[5];
  const float* fc_b    = (const float*)d_in[6];
  float* out = (float*)d_out;
  float* buf = (float*)d_ws;   // 32 MiB column-major inp (cols 0..4094 used)

  // Flags: 4 KB carved from inp column 4095 (rows 0..1023). Never consumed
  // by the scan (col 4095 is the dump column: its loads feed only h values
  // nobody reads; skew and the publisher skip it). memsetAsync resets tags
  // every launch (stream-ordered, graph-capture safe -- the harness itself
  // uses hipMemsetAsync). Blocks 4-7's publisher rows (>=1279) would land
  // past the 4KB flag region anyway; blocks 0-3 skip col 4095 explicitly.
  unsigned* flags = (unsigned*)(buf + (size_t)(WSKP - 1) * HH);
  hipMemsetAsync(flags, 0, BLKS * NCH * sizeof(unsigned), stream);

  skew_kernel<<<(WSKP * HH) / 256, 256, 0, stream>>>(x, w_in, b_in, b_state, buf);
  scan_kernel<<<BLKS, NT, 0, stream>>>(w_state, buf, buf, fc_w, fc_b, out, flags);
}